// Round 8
// baseline (111.857 us; speedup 1.0000x reference)
//
#include <hip/hip_runtime.h>

// RINN controller on MFMA (fp16 inputs, fp32 accum).
// B=131072, n_k=64, n_w=128, n_y=16, n_u=16. xi row = [y(16) | x_k(64)].
//
// S[144 x B] = Emat[144x80] @ xi^T (rows 0..127 base, 128..143 u-partial),
// then blocked back-substitution over 8 w-blocks of 16 (Dvw strictly upper):
// K=7..0: serial 16-step diag solve (fp32 VALU, shfl broadcast), then MFMA
// rank-16 updates to lower blocks and u (Duw). W B-frag is movement-free:
// k=4g+r == row 4g+r.
//
// MFMA layouts (gfx950): C/D col=lane&15 (batch), row=4*(lane>>4)+reg [m89].
// A/B 16x16x32: 8 f16/lane, k=8*(lane>>4)+i. 16x16x16: 4 f16/lane,
// k=4*(lane>>4)+i. Prep kernel materializes every fragment per-lane in ws.
//
// R8 vs R7: __launch_bounds__(512,4) caps VGPR<=128 (guarantee 4 waves/SIMD;
// diag-chain 6400cy needs >=4 waves at 1800cy issue to hide); xi float4
// loads prefetched before the staging barrier.

#define NW 128
#define NK 64
#define NY 16
#define NU 16
#define NXI 80

// ws blob layout (bytes)
#define DENSE_OFF 0      // 9 tiles x (1024 + 1024 + 512) = 23040
#define SOLVE_OFF 23040  // 36 frags x 512 = 18432 (28 offdiag + 8 Duw)
#define DIAG_OFF  41472  // 8 blk x 16 step x 16 rows x f32 = 8192
#define BLOB_BYTES 49664
#define N_PREP_THREADS 12416  // 10368 u32 (f16 pairs) + 2048 f32

typedef _Float16 f16;
typedef __attribute__((ext_vector_type(4))) _Float16 f16x4;
typedef __attribute__((ext_vector_type(8))) _Float16 f16x8;
typedef __attribute__((ext_vector_type(4))) float f32x4;

template<int I> struct Ic { static constexpr int value = I; };
template<int I, int N, typename F>
__device__ __forceinline__ void ufor(F&& f) {
    if constexpr (I < N) { f(Ic<I>{}); ufor<I + 1, N>(static_cast<F&&>(f)); }
}

__device__ __forceinline__ float emat_val(int i, int k,
                                          const float* Cv, const float* Dvy,
                                          const float* Cu, const float* Duy) {
    if (i < NW) return (k < NY) ? Dvy[i * NY + k] : Cv[i * NK + (k - NY)];
    int r = i - NW;
    return (k < NY) ? Duy[r * NY + k] : Cu[r * NK + (k - NY)];
}

__global__ void prep(const float* __restrict__ Cv, const float* __restrict__ Dvw,
                     const float* __restrict__ Dvy, const float* __restrict__ Cu,
                     const float* __restrict__ Duw, const float* __restrict__ Duy,
                     unsigned int* __restrict__ ws) {
    int id = blockIdx.x * 256 + threadIdx.x;
    if (id >= N_PREP_THREADS) return;
    if (id < DIAG_OFF / 4) {  // f16-pair sections (dense + solve frags)
        int byte = id * 4;
        float v0, v1;
        if (byte < SOLVE_OFF) {
            int T = byte / 2560, rem = byte % 2560;
            int l, i0, kbase;
            if (rem < 2048) {            // 16x16x32 chunks 0,1
                int chunk = rem >> 10, cb = rem & 1023;
                l = cb >> 4; i0 = (cb & 15) >> 1;
                kbase = chunk * 32 + (l >> 4) * 8;
            } else {                     // 16x16x16 chunk2 (k=64..79)
                int cb = rem - 2048;
                l = cb >> 3; i0 = (cb & 7) >> 1;
                kbase = 64 + (l >> 4) * 4;
            }
            int row = T * 16 + (l & 15);
            v0 = emat_val(row, kbase + i0,     Cv, Dvy, Cu, Duy);
            v1 = emat_val(row, kbase + i0 + 1, Cv, Dvy, Cu, Duy);
        } else {                         // solve A-frags (16x16x16)
            int sb = byte - SOLVE_OFF;
            int f = sb >> 9, cb = sb & 511;
            int l = cb >> 3, i0 = (cb & 7) >> 1;
            int kk = (l >> 4) * 4 + i0;
            if (f < 28) {                // (J,K) pair, f = K*(K-1)/2 + J
                int K = 1; while ((K + 1) * K / 2 <= f) K++;
                int J = f - K * (K - 1) / 2;
                int row = J * 16 + (l & 15);
                v0 = Dvw[row * NW + K * 16 + kk];
                v1 = Dvw[row * NW + K * 16 + kk + 1];
            } else {                     // Duw frag for block K
                int K = f - 28;
                int r = l & 15;
                v0 = Duw[r * NW + K * 16 + kk];
                v1 = Duw[r * NW + K * 16 + kk + 1];
            }
        }
        union { _Float16 h[2]; unsigned u; } p;
        p.h[0] = (_Float16)v0; p.h[1] = (_Float16)v1;
        ws[id] = p.u;
    } else {                             // diag coeff blob, fp32
        int d = id - DIAG_OFF / 4;       // 0..2047
        int blk = d >> 8, rem = d & 255, j = rem >> 4, ii = rem & 15;
        // Dvw strict-upper: zero for ii >= j automatically (mask for free)
        ((float*)ws)[id] = Dvw[(blk * 16 + ii) * NW + blk * 16 + j];
    }
}

__global__ __launch_bounds__(512, 4) void rinn_mfma(const float* __restrict__ xi,
                                                    const unsigned char* __restrict__ wsb,
                                                    float* __restrict__ out) {
    __shared__ __align__(16) unsigned char LDS[BLOB_BYTES];
    const int tid = threadIdx.x;
    const int lane = tid & 63;
    const int wv = tid >> 6;
    const int g = lane >> 4;       // row-group (M rows 4g..4g+3)
    const int c = lane & 15;       // batch column within tile
    const int batch0 = (blockIdx.x * 8 + wv) * 16;
    const float* __restrict__ xb = xi + (size_t)(batch0 + c) * NXI;

    // ---- prefetch xi (hides HBM latency under LDS staging + barrier) ----
    const float4 xA0 = *(const float4*)(xb + 0 * 32 + g * 8);
    const float4 xA1 = *(const float4*)(xb + 0 * 32 + g * 8 + 4);
    const float4 xB0 = *(const float4*)(xb + 1 * 32 + g * 8);
    const float4 xB1 = *(const float4*)(xb + 1 * 32 + g * 8 + 4);
    const float4 xC  = *(const float4*)(xb + 64 + g * 4);

    {   // stage blob -> LDS (3104 uint4 = 49664 B)
        const uint4* src = (const uint4*)wsb;
        uint4* dst = (uint4*)LDS;
        ufor<0, 6>([&](auto IT) { dst[IT.value * 512 + tid] = src[IT.value * 512 + tid]; });
        if (tid < 32) dst[3072 + tid] = src[3072 + tid];
    }
    __syncthreads();

    f32x4 acc[9];
    ufor<0, 9>([&](auto T) { acc[T.value] = (f32x4){0.f, 0.f, 0.f, 0.f}; });

    // ---- dense: chunks 0,1 (16x16x32, k=0..63) ----
    ufor<0, 2>([&](auto KC) {
        constexpr int kc = KC.value;
        const float4 xa = (kc == 0) ? xA0 : xB0;
        const float4 xc2 = (kc == 0) ? xA1 : xB1;
        f16x8 Bf;
        Bf[0] = (f16)xa.x; Bf[1] = (f16)xa.y; Bf[2] = (f16)xa.z; Bf[3] = (f16)xa.w;
        Bf[4] = (f16)xc2.x; Bf[5] = (f16)xc2.y; Bf[6] = (f16)xc2.z; Bf[7] = (f16)xc2.w;
        ufor<0, 9>([&](auto T) {
            constexpr int t = T.value;
            const f16x8 Af = *(const f16x8*)&LDS[t * 2560 + kc * 1024 + lane * 16];
            acc[t] = __builtin_amdgcn_mfma_f32_16x16x32_f16(Af, Bf, acc[t], 0, 0, 0);
        });
    });
    // ---- dense: chunk2 (16x16x16, k=64..79) ----
    {
        f16x4 Bf;
        Bf[0] = (f16)xC.x; Bf[1] = (f16)xC.y; Bf[2] = (f16)xC.z; Bf[3] = (f16)xC.w;
        ufor<0, 9>([&](auto T) {
            constexpr int t = T.value;
            const f16x4 Af = *(const f16x4*)&LDS[t * 2560 + 2048 + lane * 8];
            acc[t] = __builtin_amdgcn_mfma_f32_16x16x16f16(Af, Bf, acc[t], 0, 0, 0);
        });
    }

    const unsigned char* __restrict__ diagp = &LDS[DIAG_OFF + g * 16];

    // ---- blocked back-substitution, K = 7..0 ----
    ufor<0, 8>([&](auto QQ) {
        constexpr int K = 7 - QQ.value;
        // serial diag solve (fp32), local rows j = 15..0
        ufor<0, 16>([&](auto JJ) {
            constexpr int j = 15 - JJ.value;
            constexpr int gj = j >> 2, rj = j & 3;
            float s = __shfl(acc[K][rj], gj * 16 + c, 64);
            float w = fmaxf(s, 0.f);
            const f32x4 d = *(const f32x4*)(diagp + (K * 16 + j) * 64);
            acc[K][0] = fmaf(d[0], w, acc[K][0]);
            acc[K][1] = fmaf(d[1], w, acc[K][1]);
            acc[K][2] = fmaf(d[2], w, acc[K][2]);
            acc[K][3] = fmaf(d[3], w, acc[K][3]);
        });
        // W B-fragment: k=4g+r == this lane's rows; no cross-lane movement
        f16x4 Wf;
        Wf[0] = (f16)fmaxf(acc[K][0], 0.f);
        Wf[1] = (f16)fmaxf(acc[K][1], 0.f);
        Wf[2] = (f16)fmaxf(acc[K][2], 0.f);
        Wf[3] = (f16)fmaxf(acc[K][3], 0.f);
        // u += Duw[:,K] @ W_K
        {
            const f16x4 Af = *(const f16x4*)&LDS[SOLVE_OFF + (28 + K) * 512 + lane * 8];
            acc[8] = __builtin_amdgcn_mfma_f32_16x16x16f16(Af, Wf, acc[8], 0, 0, 0);
        }
        // S_J += Dvw[J,K] @ W_K for J < K
        ufor<0, K>([&](auto JB) {
            constexpr int J = JB.value;
            const f16x4 Af = *(const f16x4*)&LDS[SOLVE_OFF + (K * (K - 1) / 2 + J) * 512 + lane * 8];
            acc[J] = __builtin_amdgcn_mfma_f32_16x16x16f16(Af, Wf, acc[J], 0, 0, 0);
        });
    });

    // ---- write u tile: lane (g,c) holds u[4g..4g+3] of batch (batch0+c) ----
    float4 o = make_float4(acc[8][0], acc[8][1], acc[8][2], acc[8][3]);
    *(float4*)(out + (size_t)(batch0 + c) * NU + g * 4) = o;
}

extern "C" void kernel_launch(void* const* d_in, const int* in_sizes, int n_in,
                              void* d_out, int out_size, void* d_ws, size_t ws_size,
                              hipStream_t stream) {
    const float* xi  = (const float*)d_in[0];
    const float* Cv  = (const float*)d_in[1];
    const float* Dvw = (const float*)d_in[2];
    const float* Dvy = (const float*)d_in[3];
    const float* Cu  = (const float*)d_in[4];
    const float* Duw = (const float*)d_in[5];
    const float* Duy = (const float*)d_in[6];
    float* out = (float*)d_out;

    const int B = in_sizes[0] / NXI;  // 131072

    prep<<<(N_PREP_THREADS + 255) / 256, 256, 0, stream>>>(
        Cv, Dvw, Dvy, Cu, Duw, Duy, (unsigned int*)d_ws);
    rinn_mfma<<<B / 128, 512, 0, stream>>>(
        xi, (const unsigned char*)d_ws, out);
}